// Round 7
// baseline (11125.267 us; speedup 1.0000x reference)
//
#include <hip/hip_runtime.h>
#include <math.h>

using ushort_t = unsigned short;
using ull = unsigned long long;
using short8 = __attribute__((ext_vector_type(8))) short;
using floatx16 = __attribute__((ext_vector_type(16))) float;

constexpr int kB = 512, kT = 256, kH = 512, kHor = 64;
constexpr int NG = 4 * kH;
constexpr int NBLK = 256;

// LDS plane offsets (shorts): per buffer 6 planes x 4096
constexpr int P_A0 = 0;        // a0 hi; lo at +4096
constexpr int P_A1 = 8192;     // a1 hi; lo at +4096
constexpr int P_B  = 16384;    // b  hi; lo at +4096
constexpr int BUFS = 24576;    // buffer stride in shorts (2 buffers)

// s_waitcnt immediates (gfx9 encoding: vm[3:0]|exp[6:4]|lgkm[11:8]|vm[15:14])
#define WC_VM0_LGKM0 0x0070    // vmcnt(0) + lgkmcnt(0), expcnt ignored
#define WC_LGKM0     0xC07F    // lgkmcnt(0) only, vmcnt stays in flight

template<int A, int B> struct Tag { static constexpr int H0 = A, H1 = B; };

__device__ __forceinline__ ushort_t f2bf(float v) {
  unsigned u = __builtin_bit_cast(unsigned, v);
  return (ushort_t)((u + 0x7FFFu + ((u >> 16) & 1u)) >> 16);
}
__device__ __forceinline__ float bf2f(ushort_t b) {
  unsigned u = (unsigned)b << 16;
  return __builtin_bit_cast(float, u);
}
__device__ __forceinline__ float sig_(float x) { return 1.0f / (1.0f + __expf(-x)); }

__device__ __forceinline__ void async16(const ushort_t* g, ushort_t* l) {
  __builtin_amdgcn_global_load_lds(
      (const __attribute__((address_space(1))) void*)g,
      (__attribute__((address_space(3))) void*)l, 16, 0, 0);
}

__device__ __forceinline__ ull ald64(const void* p) {
  return __hip_atomic_load((const ull*)p, __ATOMIC_RELAXED, __HIP_MEMORY_SCOPE_AGENT);
}
__device__ __forceinline__ void ast64(void* p, ull v) {
  __hip_atomic_store((ull*)p, v, __ATOMIC_RELAXED, __HIP_MEMORY_SCOPE_AGENT);
}
__device__ __forceinline__ void astf(float* p, float v) {
  __hip_atomic_store(p, v, __ATOMIC_RELAXED, __HIP_MEMORY_SCOPE_AGENT);
}
__device__ __forceinline__ unsigned aldu(const unsigned* p) {
  return __hip_atomic_load(p, __ATOMIC_RELAXED, __HIP_MEMORY_SCOPE_AGENT);
}
__device__ __forceinline__ void astu(unsigned* p, unsigned v) {
  __hip_atomic_store(p, v, __ATOMIC_RELAXED, __HIP_MEMORY_SCOPE_AGENT);
}

struct PP {
  const ushort_t *w0e_hi, *w0e_lo, *w1e_hi, *w1e_lo;
  const ushort_t *w0d_hi, *w0d_lo, *w1d_hi, *w1d_lo;
  ushort_t *h0hi0, *h0hi1, *h0lo0, *h0lo1;
  ushort_t *h1hi0, *h1hi1, *h1lo0, *h1lo1;
  const float *be0, *be1, *bd0, *bd1, *wxe, *wxd;
  const float *x, *headW, *hb;
  float *hpart;        // [n][32] per-mb head partials
  float *out;
  unsigned *slots;     // [256] arrival counters
  unsigned *gen;       // broadcast release word
  unsigned *xcdcnt;    // [8] per-XCD claim counters
};

struct Ph {
  const ushort_t *w0hi, *w0lo, *w1hi, *w1lo;
  const ushort_t *b0hi, *b0lo, *b1hi, *b1lo;
  const float *bias0, *wx0, *bias1;
  ushort_t *H0hi, *H0lo, *H1hi, *H1lo;
  int xmode;    // 0: x[:,tcol]; 1: head from hpart
  int tcol;
  int outcol;   // >=0: lanes wm==0 write out[:,outcol] = xv
  int do_head;  // L1 epilogue stores head partials
};

__global__ __launch_bounds__(256, 1) void lstm_persist(PP P) {
  __shared__ __align__(16) ushort_t sm[2 * BUFS];     // 96 KB
  __shared__ ushort_t hshi[64 * 18];
  __shared__ ushort_t hslo[64 * 18];
  __shared__ unsigned sclaim;

  const int tid = threadIdx.x;
  const int bx = blockIdx.x;

  // ---- XCD discovery + tile claim: weights XCD-L2-resident (verified R6) ----
  if (tid == 0) {
    unsigned xcc;
    asm volatile("s_getreg_b32 %0, hwreg(HW_REG_XCC_ID)" : "=s"(xcc));
    xcc &= 7u;
    unsigned slot = atomicAdd(&P.xcdcnt[xcc], 1u) & 31u;
    sclaim = (xcc << 5) | slot;
  }
  __syncthreads();
  const unsigned cl = sclaim;
  const int nb = cl & 7;
  const int mb = (cl >> 5) * 4 + ((cl >> 3) & 3);
  const int m0blk = mb * 64;
  const int n0blk = nb * 64;

  const int wv = tid >> 6;
  const int ln = tid & 63;
  const int l31 = ln & 31;
  const int half = ln >> 5;
  const int wm = wv & 1, wn = wv >> 1;
  const int m0w = wm * 32, n0w = wn * 32;
  const int r8 = ln >> 3;
  const int k8s = (ln & 7) ^ r8;
  const int ng = n0blk + n0w + l31;

  ushort_t* h0hi[2] = {P.h0hi0, P.h0hi1};
  ushort_t* h0lo[2] = {P.h0lo0, P.h0lo1};
  ushort_t* h1hi[2] = {P.h1hi0, P.h1hi1};
  ushort_t* h1lo[2] = {P.h1lo0, P.h1lo1};

  float cr0[4] = {0.f, 0.f, 0.f, 0.f};
  float cr1[4] = {0.f, 0.f, 0.f, 0.f};
  unsigned phase = 0;

  // ---- low-contention grid barrier: block 0 aggregates, leaders poll gen ----
  auto gbar = [&]() {
    asm volatile("" ::: "memory");
    __builtin_amdgcn_s_waitcnt(0);      // my h/hpart stores at coherent point
    __syncthreads();
    ++phase;
    if (bx == 0) {
      if (tid == 0) astu(&P.slots[0], phase);
      while (aldu(&P.slots[tid]) < phase) __builtin_amdgcn_s_sleep(1);
      __syncthreads();
      if (tid == 0) astu(P.gen, phase);
    } else {
      if (tid == 0) {
        astu(&P.slots[bx], phase);
        while (aldu(P.gen) < phase) __builtin_amdgcn_s_sleep(4);
      }
    }
    __syncthreads();
    asm volatile("" ::: "memory");
  };

  auto cell_epi = [&](floatx16& acc, float* cr, const float* bias, const float* wx,
                      bool useX, float xv, ushort_t* Hhi, ushort_t* Hlo) {
    #pragma unroll
    for (int rg = 0; rg < 4; ++rg) {
      const int jl = wm * 8 + rg * 2 + half;
      const int jg = mb * 16 + jl;
      const float4 bi = *(const float4*)&bias[jg * 4];
      float gi = acc[rg * 4 + 0] + bi.x;
      float gf = acc[rg * 4 + 1] + bi.y;
      float gg = acc[rg * 4 + 2] + bi.z;
      float go = acc[rg * 4 + 3] + bi.w;
      if (useX) {
        const float4 wx4 = *(const float4*)&wx[jg * 4];
        gi += xv * wx4.x; gf += xv * wx4.y; gg += xv * wx4.z; go += xv * wx4.w;
      }
      const float i_ = sig_(gi), f_ = sig_(gf), g_ = tanhf(gg), o_ = sig_(go);
      const float cn = f_ * cr[rg] + i_ * g_;
      cr[rg] = cn;
      const float hn = o_ * tanhf(cn);
      const ushort_t hhi = f2bf(hn);
      const ushort_t hlo = f2bf(hn - bf2f(hhi));
      const int nbk = n0w + l31;
      hshi[nbk * 18 + jl] = hhi;
      hslo[nbk * 18 + jl] = hlo;
    }
    __syncthreads();
    {
      const int nbk = tid >> 2, jq = (tid & 3) * 4;
      ull hv = (ull)hshi[nbk * 18 + jq] | ((ull)hshi[nbk * 18 + jq + 1] << 16)
             | ((ull)hshi[nbk * 18 + jq + 2] << 32) | ((ull)hshi[nbk * 18 + jq + 3] << 48);
      ull lv = (ull)hslo[nbk * 18 + jq] | ((ull)hslo[nbk * 18 + jq + 1] << 16)
             | ((ull)hslo[nbk * 18 + jq + 2] << 32) | ((ull)hslo[nbk * 18 + jq + 3] << 48);
      ast64(&Hhi[(size_t)(n0blk + nbk) * kH + mb * 16 + jq], hv);
      ast64(&Hlo[(size_t)(n0blk + nbk) * kH + mb * 16 + jq], lv);
    }
  };

  auto run_phase = [&](auto tag, const Ph& ph) {
    constexpr int HAS0 = decltype(tag)::H0;
    constexpr int HAS1 = decltype(tag)::H1;
    constexpr int nkt = HAS1 ? 16 : 8;

    floatx16 acc0, acc1;
    #pragma unroll
    for (int i = 0; i < 16; ++i) { acc0[i] = 0.f; acc1[i] = 0.f; }

    auto dma_kt = [&](int kt, int buf) {
      if (wv <= 1) {
        ushort_t* bb = &sm[buf * BUFS];
        if (HAS0 && kt < 8) {
          const ushort_t* w = wv ? ph.w0lo : ph.w0hi;
          const ushort_t* g0 = w + (size_t)(m0blk + r8) * 512 + kt * 64 + k8s * 8;
          ushort_t* lb = bb + P_A0 + wv * 4096;
          #pragma unroll
          for (int i = 0; i < 8; ++i) async16(g0 + (size_t)i * 8 * 512, lb + i * 512);
        }
        if (HAS1) {
          const ushort_t* w = wv ? ph.w1lo : ph.w1hi;
          const ushort_t* g0 = w + (size_t)(m0blk + r8) * 1024 + kt * 64 + k8s * 8;
          ushort_t* lb = bb + P_A1 + wv * 4096;
          #pragma unroll
          for (int i = 0; i < 8; ++i) async16(g0 + (size_t)i * 8 * 1024, lb + i * 512);
        }
      }
    };
    auto bloadTo = [&](int kt, ull* br) {
      if (wv >= 2) {
        const ushort_t* s = (kt < 8) ? (wv == 2 ? ph.b0hi : ph.b0lo)
                                     : (wv == 2 ? ph.b1hi : ph.b1lo);
        const int col0 = (kt & 7) * 64;
        const ushort_t* g0 = s + (size_t)(n0blk + r8) * kH + col0 + k8s * 8;
        #pragma unroll
        for (int i = 0; i < 8; ++i) {
          const ushort_t* gp = g0 + (size_t)i * 8 * kH;
          br[2 * i]     = ald64(gp);
          br[2 * i + 1] = ald64(gp + 4);
        }
      }
    };
    auto bwrite = [&](int buf, const ull* br) {
      if (wv >= 2) {
        ushort_t* lb = &sm[buf * BUFS] + P_B + (wv - 2) * 4096;
        #pragma unroll
        for (int i = 0; i < 8; ++i) {
          int4 v;
          v.x = (int)(unsigned)br[2 * i];
          v.y = (int)(unsigned)(br[2 * i] >> 32);
          v.z = (int)(unsigned)br[2 * i + 1];
          v.w = (int)(unsigned)(br[2 * i + 1] >> 32);
          *(int4*)(lb + i * 512 + ln * 8) = v;
        }
      }
    };
    auto compute = [&](int kt, int buf) {
      const ushort_t* base = &sm[buf * BUFS];
      #pragma unroll
      for (int ks = 0; ks < 4; ++ks) {
        const int k8 = ks * 2 + half;
        const int sw = k8 ^ (l31 & 7);
        const int qa = ((m0w + l31) * 8 + sw) * 8;
        const int qb = ((n0w + l31) * 8 + sw) * 8;
        short8 bhi = *(const short8*)(base + P_B + qb);
        short8 blo = *(const short8*)(base + P_B + 4096 + qb);
        if (HAS0 && kt < 8) {
          short8 ahi = *(const short8*)(base + P_A0 + qa);
          short8 alo = *(const short8*)(base + P_A0 + 4096 + qa);
          acc0 = __builtin_amdgcn_mfma_f32_32x32x16_bf16(alo, bhi, acc0, 0, 0, 0);
          acc0 = __builtin_amdgcn_mfma_f32_32x32x16_bf16(ahi, blo, acc0, 0, 0, 0);
          acc0 = __builtin_amdgcn_mfma_f32_32x32x16_bf16(ahi, bhi, acc0, 0, 0, 0);
        }
        if (HAS1) {
          short8 ahi = *(const short8*)(base + P_A1 + qa);
          short8 alo = *(const short8*)(base + P_A1 + 4096 + qa);
          acc1 = __builtin_amdgcn_mfma_f32_32x32x16_bf16(alo, bhi, acc1, 0, 0, 0);
          acc1 = __builtin_amdgcn_mfma_f32_32x32x16_bf16(ahi, blo, acc1, 0, 0, 0);
          acc1 = __builtin_amdgcn_mfma_f32_32x32x16_bf16(ahi, bhi, acc1, 0, 0, 0);
        }
      }
    };

    // ---- k-loop: raw barriers, 2-deep B prefetch kept in flight across them ----
    ull brA[16], brB[16];
    bloadTo(0, brA);
    bloadTo(1, brB);
    dma_kt(0, 0);
    if (wv >= 2) {
      bwrite(0, brA);                       // compiler waits brA's loads only
      asm volatile("" ::: "memory");
      __builtin_amdgcn_s_waitcnt(WC_LGKM0); // ds_writes visible; brB stays in flight
    } else {
      asm volatile("" ::: "memory");
      __builtin_amdgcn_s_waitcnt(WC_VM0_LGKM0);  // dma(0) deposited
    }
    asm volatile("" ::: "memory");
    __builtin_amdgcn_s_barrier();
    asm volatile("" ::: "memory");

    #pragma unroll
    for (int kt = 0; kt < nkt; ++kt) {
      const int cur = kt & 1, nxt = cur ^ 1;
      ull* brN = (kt & 1) ? brB : brA;      // receives B(kt+2)
      ull* brW = (kt & 1) ? brA : brB;      // holds B(kt+1)
      if (kt + 2 < nkt) bloadTo(kt + 2, brN);
      if (kt + 1 < nkt) dma_kt(kt + 1, nxt);
      compute(kt, cur);
      if (kt + 1 < nkt) bwrite(nxt, brW);
      if (wv >= 2) {
        asm volatile("" ::: "memory");
        __builtin_amdgcn_s_waitcnt(WC_LGKM0);      // publish ds_writes, keep vm in flight
      } else {
        asm volatile("" ::: "memory");
        __builtin_amdgcn_s_waitcnt(WC_VM0_LGKM0);  // dma(kt+1) deposited (L2-hit)
      }
      asm volatile("" ::: "memory");
      __builtin_amdgcn_s_barrier();
      asm volatile("" ::: "memory");
    }

    if (HAS0) {
      float xv;
      if (ph.xmode == 0) {
        xv = P.x[(size_t)ng * kT + ph.tcol];
      } else {
        float s = P.hb[0];
        const float* hp = &P.hpart[(size_t)ng * 32];
        #pragma unroll
        for (int i = 0; i < 16; ++i) {
          ull v = ald64(hp + 2 * i);
          s += __builtin_bit_cast(float, (unsigned)v)
             + __builtin_bit_cast(float, (unsigned)(v >> 32));
        }
        xv = s;
      }
      cell_epi(acc0, cr0, ph.bias0, ph.wx0, true, xv, ph.H0hi, ph.H0lo);
      if (ph.outcol >= 0 && wm == 0)
        P.out[(size_t)ng * kHor + ph.outcol] = xv;
      __syncthreads();
    }
    if (HAS1) {
      cell_epi(acc1, cr1, ph.bias1, nullptr, false, 0.f, ph.H1hi, ph.H1lo);
      if (ph.do_head && tid < 64) {
        float s = 0.f;
        #pragma unroll
        for (int jb = 0; jb < 16; ++jb)
          s += (bf2f(hshi[tid * 18 + jb]) + bf2f(hslo[tid * 18 + jb]))
               * P.headW[mb * 16 + jb];
        astf(&P.hpart[(size_t)(n0blk + tid) * 32 + mb], s);
      }
      __syncthreads();
    }
  };

  // ---------- encoder: merged wavefront L0[p] || L1[p-1] ----------
  for (int p = 0; p <= 256; ++p) {
    const int rd = p & 1, wr = rd ^ 1;
    Ph ph = {};
    ph.w0hi = P.w0e_hi; ph.w0lo = P.w0e_lo;
    ph.w1hi = P.w1e_hi; ph.w1lo = P.w1e_lo;
    ph.b0hi = h0hi[rd]; ph.b0lo = h0lo[rd];
    ph.b1hi = h1hi[rd]; ph.b1lo = h1lo[rd];
    ph.bias0 = P.be0; ph.wx0 = P.wxe; ph.bias1 = P.be1;
    ph.H0hi = h0hi[wr]; ph.H0lo = h0lo[wr];
    ph.H1hi = h1hi[wr]; ph.H1lo = h1lo[wr];
    ph.xmode = 0; ph.tcol = (p < 256) ? p : 0;
    ph.outcol = -1; ph.do_head = 0;
    if (p == 0)        run_phase(Tag<1, 0>{}, ph);
    else if (p == 256) run_phase(Tag<0, 1>{}, ph);
    else               run_phase(Tag<1, 1>{}, ph);
    gbar();
  }
  // h0 final parity 0, h1 final parity 1

  // ---------- decoder ----------
  for (int t = 0; t < kHor; ++t) {
    const int r0 = t & 1, w0 = r0 ^ 1;
    const int r1 = (t + 1) & 1, w1 = t & 1;
    {
      Ph a = {};
      a.w0hi = P.w0d_hi; a.w0lo = P.w0d_lo;
      a.b0hi = h0hi[r0]; a.b0lo = h0lo[r0];
      a.bias0 = P.bd0; a.wx0 = P.wxd;
      a.H0hi = h0hi[w0]; a.H0lo = h0lo[w0];
      a.xmode = (t == 0) ? 0 : 1; a.tcol = 255;
      a.outcol = (t >= 1) ? (t - 1) : -1;
      a.do_head = 0;
      run_phase(Tag<1, 0>{}, a);
      gbar();
    }
    {
      Ph b = {};
      b.w1hi = P.w1d_hi; b.w1lo = P.w1d_lo;
      b.b0hi = h0hi[w0]; b.b0lo = h0lo[w0];
      b.b1hi = h1hi[r1]; b.b1lo = h1lo[r1];
      b.bias1 = P.bd1;
      b.H1hi = h1hi[w1]; b.H1lo = h1lo[w1];
      b.xmode = 0; b.tcol = 0; b.outcol = -1; b.do_head = 1;
      run_phase(Tag<0, 1>{}, b);
      gbar();
    }
  }

  // final output column 63
  if (mb == 0 && tid < 64) {
    const int n = n0blk + tid;
    float s = P.hb[0];
    const float* hp = &P.hpart[(size_t)n * 32];
    #pragma unroll
    for (int i = 0; i < 16; ++i) {
      ull v = ald64(hp + 2 * i);
      s += __builtin_bit_cast(float, (unsigned)v)
         + __builtin_bit_cast(float, (unsigned)(v >> 32));
    }
    P.out[(size_t)n * kHor + 63] = s;
  }
}

// ---- prep kernels ----
__global__ void prep_w(const float* __restrict__ s0, const float* __restrict__ s1,
                       ushort_t* __restrict__ hi, ushort_t* __restrict__ lo, int Kw) {
  const int k = blockIdx.x * 256 + threadIdx.x;
  const int r = blockIdx.y;                 // packed row j*4+g
  const int j = r >> 2, g = r & 3;
  const int srow = g * kH + j;
  const float v = (k < kH) ? s0[(size_t)srow * kH + k]
                           : s1[(size_t)srow * kH + (k - kH)];
  const ushort_t h = f2bf(v);
  const ushort_t l = f2bf(v - bf2f(h));
  hi[(size_t)r * Kw + k] = h;
  lo[(size_t)r * Kw + k] = l;
}

__global__ void prep_vec(const float* __restrict__ src, float* __restrict__ dst) {
  const int t = blockIdx.x * 256 + threadIdx.x;   // 2048
  const int j = t >> 2, g = t & 3;
  dst[t] = src[g * kH + j];
}

__global__ void init_zero(ushort_t* p0, ushort_t* p1, ushort_t* p2, ushort_t* p3,
                          ushort_t* p4, ushort_t* p5, ushort_t* p6, ushort_t* p7,
                          unsigned* slots, unsigned* xcdcnt) {
  const int i = blockIdx.x * 256 + threadIdx.x;   // 262144
  p0[i] = 0; p1[i] = 0; p2[i] = 0; p3[i] = 0;
  p4[i] = 0; p5[i] = 0; p6[i] = 0; p7[i] = 0;
  if (i < NBLK + 8) slots[i] = 0u;                // slots + gen
  if (i < 8) xcdcnt[i] = 0u;
}

extern "C" void kernel_launch(void* const* d_in, const int* in_sizes, int n_in,
                              void* d_out, int out_size, void* d_ws, size_t ws_size,
                              hipStream_t stream) {
  const float* x     = (const float*)d_in[0];
  const float* eWih0 = (const float*)d_in[1];
  const float* eWhh0 = (const float*)d_in[2];
  const float* eb0   = (const float*)d_in[3];
  const float* eWih1 = (const float*)d_in[4];
  const float* eWhh1 = (const float*)d_in[5];
  const float* eb1   = (const float*)d_in[6];
  const float* dWih0 = (const float*)d_in[7];
  const float* dWhh0 = (const float*)d_in[8];
  const float* db0   = (const float*)d_in[9];
  const float* dWih1 = (const float*)d_in[10];
  const float* dWhh1 = (const float*)d_in[11];
  const float* db1   = (const float*)d_in[12];
  const float* hW    = (const float*)d_in[13];
  const float* hb    = (const float*)d_in[14];
  float* out = (float*)d_out;

  char* w = (char*)d_ws;
  size_t off = 0;
  auto aus = [&](size_t n) { ushort_t* p = (ushort_t*)(w + off); off += ((n * 2 + 255) & ~(size_t)255); return p; };
  auto afl = [&](size_t n) { float* p = (float*)(w + off); off += ((n * 4 + 255) & ~(size_t)255); return p; };

  ushort_t* w0e_hi = aus((size_t)NG * 512);  ushort_t* w0e_lo = aus((size_t)NG * 512);
  ushort_t* w1e_hi = aus((size_t)NG * 1024); ushort_t* w1e_lo = aus((size_t)NG * 1024);
  ushort_t* w0d_hi = aus((size_t)NG * 512);  ushort_t* w0d_lo = aus((size_t)NG * 512);
  ushort_t* w1d_hi = aus((size_t)NG * 1024); ushort_t* w1d_lo = aus((size_t)NG * 1024);
  ushort_t* h0hi[2] = {aus(kB * kH), aus(kB * kH)};
  ushort_t* h0lo[2] = {aus(kB * kH), aus(kB * kH)};
  ushort_t* h1hi[2] = {aus(kB * kH), aus(kB * kH)};
  ushort_t* h1lo[2] = {aus(kB * kH), aus(kB * kH)};
  float* be0 = afl(NG); float* be1 = afl(NG);
  float* bd0 = afl(NG); float* bd1 = afl(NG);
  float* wxe = afl(NG); float* wxd = afl(NG);
  float* hpart = afl((size_t)kB * 32);
  unsigned* slots = (unsigned*)afl(NBLK + 8);
  unsigned* gen = slots + NBLK;
  unsigned* xcdcnt = (unsigned*)afl(8);

  prep_w<<<dim3(2, NG), 256, 0, stream>>>(eWhh0, eWhh0, w0e_hi, w0e_lo, 512);
  prep_w<<<dim3(4, NG), 256, 0, stream>>>(eWih1, eWhh1, w1e_hi, w1e_lo, 1024);
  prep_w<<<dim3(2, NG), 256, 0, stream>>>(dWhh0, dWhh0, w0d_hi, w0d_lo, 512);
  prep_w<<<dim3(4, NG), 256, 0, stream>>>(dWih1, dWhh1, w1d_hi, w1d_lo, 1024);
  prep_vec<<<8, 256, 0, stream>>>(eb0, be0);
  prep_vec<<<8, 256, 0, stream>>>(eb1, be1);
  prep_vec<<<8, 256, 0, stream>>>(db0, bd0);
  prep_vec<<<8, 256, 0, stream>>>(db1, bd1);
  prep_vec<<<8, 256, 0, stream>>>(eWih0, wxe);
  prep_vec<<<8, 256, 0, stream>>>(dWih0, wxd);
  init_zero<<<1024, 256, 0, stream>>>(h0hi[0], h0hi[1], h0lo[0], h0lo[1],
                                      h1hi[0], h1hi[1], h1lo[0], h1lo[1],
                                      slots, xcdcnt);

  PP P;
  P.w0e_hi = w0e_hi; P.w0e_lo = w0e_lo; P.w1e_hi = w1e_hi; P.w1e_lo = w1e_lo;
  P.w0d_hi = w0d_hi; P.w0d_lo = w0d_lo; P.w1d_hi = w1d_hi; P.w1d_lo = w1d_lo;
  P.h0hi0 = h0hi[0]; P.h0hi1 = h0hi[1]; P.h0lo0 = h0lo[0]; P.h0lo1 = h0lo[1];
  P.h1hi0 = h1hi[0]; P.h1hi1 = h1hi[1]; P.h1lo0 = h1lo[0]; P.h1lo1 = h1lo[1];
  P.be0 = be0; P.be1 = be1; P.bd0 = bd0; P.bd1 = bd1; P.wxe = wxe; P.wxd = wxd;
  P.x = x; P.headW = hW; P.hb = hb;
  P.hpart = hpart; P.out = out; P.slots = slots; P.gen = gen;
  P.xcdcnt = xcdcnt;

  lstm_persist<<<dim3(NBLK), dim3(256), 0, stream>>>(P);
}